// Round 6
// baseline (154.920 us; speedup 1.0000x reference)
//
#include <hip/hip_runtime.h>

typedef _Float16 half_t;
typedef __attribute__((ext_vector_type(8))) _Float16 half8;
typedef __attribute__((ext_vector_type(4))) _Float16 half4;
typedef __attribute__((ext_vector_type(2))) _Float16 half2_t;
typedef __attribute__((ext_vector_type(4))) float floatx4;
typedef __attribute__((ext_vector_type(16))) float floatx16;

#define MFMA32(A, B, C) __builtin_amdgcn_mfma_f32_32x32x16_f16((A), (B), (C), 0, 0, 0)

// ----------------------------------------------------------------- k_qkv ----
// Per (t-tile tx, window w), 32x32x16 MFMA:
//   D1^T[o 0..127][t 0..127] = W[0:128] . Xw^T   (q,k — transposed form)
//   D2  [t 0..127][o 0..63]  = Xw . W[128:192]^T (v — natural form)
// q,k: bias -> half4 LDS (E1[t][o]) -> b128 coalesced global [win][t][c],
// with post-bias column sums accumulated during read-back. v: half4 direct
// stores to vT [win][c][t].
__global__ __launch_bounds__(256, 3) void k_qkv(
    const float* __restrict__ x, const float* __restrict__ W,
    const float* __restrict__ bias, half_t* __restrict__ q,
    half_t* __restrict__ k, half_t* __restrict__ vT,
    float* __restrict__ qp, float* __restrict__ kp) {
  __shared__ __align__(16) char smem[46080];  // Xs+Ws | E1 (overlaid)
  half_t (*Xs)[72] = (half_t (*)[72])smem;            // 18432 B [t][c]
  half_t (*Ws)[72] = (half_t (*)[72])(smem + 18432);  // 27648 B [o][c]
  half_t (*E1)[136] = (half_t (*)[136])smem;          // 34816 B [t][o], after barrier
  __shared__ float qs_l[64], ks_l[64];

  const int w = blockIdx.y, tx = blockIdx.x;
  const int t0 = tx * 128;
  const int ih = w >> 3, iw = w & 7;
  const int xbase = ih * 8192 + iw * 32;
  const int tid = threadIdx.x;

  if (tid < 64) { qs_l[tid] = 0.f; ks_l[tid] = 0.f; }

  // stage Xs[t][c]: thread owns one t (x2 c-halves); 32 coalesced f32 loads
  // -> 4 b128 LDS writes
  {
    const int t = tid & 127, cg = tid >> 7;
    const int tg = t0 + t;
    const int xoff = xbase + (tg >> 5) * 256 + (tg & 31);
    half8 h8[4];
    #pragma unroll
    for (int m = 0; m < 32; m++)
      h8[m >> 3][m & 7] = (half_t)x[(cg * 32 + m) * 65536 + xoff];
    #pragma unroll
    for (int g = 0; g < 4; g++)
      *(half8*)&Xs[t][cg * 32 + g * 8] = h8[g];
  }
  // stage Ws[o][c] (fp32 -> fp16), float4 -> half4
  for (int i = tid; i < 3072; i += 256) {
    const int o = i >> 4, c4 = (i & 15) * 4;
    const floatx4 v = *(const floatx4*)&W[o * 64 + c4];
    half4 hv;
    #pragma unroll
    for (int p = 0; p < 4; p++) hv[p] = (half_t)v[p];
    *(half4*)&Ws[o][c4] = hv;
  }
  __syncthreads();

  const int wave = tid >> 6, lane = tid & 63;
  const int ln31 = lane & 31;
  const int hk8 = (lane >> 5) * 8, hk4 = (lane >> 5) * 4;
  const int w32 = wave * 32;

  floatx16 d1[4], dv[2];
  #pragma unroll
  for (int tt = 0; tt < 4; tt++)
    #pragma unroll
    for (int r = 0; r < 16; r++) d1[tt][r] = 0.f;
  #pragma unroll
  for (int ot = 0; ot < 2; ot++)
    #pragma unroll
    for (int r = 0; r < 16; r++) dv[ot][r] = 0.f;

  #pragma unroll
  for (int kk = 0; kk < 4; kk++) {
    const int ko = kk * 16 + hk8;
    const half8 aW = *(const half8*)&Ws[w32 + ln31][ko];     // A: W rows (m=o)
    half8 bX[4];
    #pragma unroll
    for (int tt = 0; tt < 4; tt++)
      bX[tt] = *(const half8*)&Xs[tt * 32 + ln31][ko];       // B: X rows (n=t)
    const half8 bV0 = *(const half8*)&Ws[128 + ln31][ko];    // B: Wv rows (n=o)
    const half8 bV1 = *(const half8*)&Ws[160 + ln31][ko];
    #pragma unroll
    for (int tt = 0; tt < 4; tt++) d1[tt] = MFMA32(aW, bX[tt], d1[tt]);
    dv[0] = MFMA32(bX[wave], bV0, dv[0]);                    // A: X (m=t strip)
    dv[1] = MFMA32(bX[wave], bV1, dv[1]);
  }

  // v epilogue: direct half4 stores (col=o fixed per lane, rows t 4-groups)
  {
    const int wbase = w * 65536;
    #pragma unroll
    for (int ot = 0; ot < 2; ot++) {
      const int o = ot * 32 + ln31;
      const float bv = bias[128 + o];
      #pragma unroll
      for (int g = 0; g < 4; g++) {
        const int tl = w32 + g * 8 + hk4;
        half4 pk;
        #pragma unroll
        for (int p = 0; p < 4; p++) pk[p] = (half_t)(dv[ot][g * 4 + p] + bv);
        *(half4*)&vT[wbase + o * 1024 + t0 + tl] = pk;
      }
    }
  }

  __syncthreads();  // all Xs/Ws reads done -> E1 may overlay

  // q,k epilogue: bias + half4 -> E1[t][o]
  {
    floatx4 b4[4];
    #pragma unroll
    for (int g = 0; g < 4; g++)
      b4[g] = *(const floatx4*)&bias[w32 + g * 8 + hk4];
    #pragma unroll
    for (int tt = 0; tt < 4; tt++) {
      const int t = tt * 32 + ln31;
      #pragma unroll
      for (int g = 0; g < 4; g++) {
        half4 pk;
        #pragma unroll
        for (int p = 0; p < 4; p++)
          pk[p] = (half_t)(d1[tt][g * 4 + p] + b4[g][p]);
        *(half4*)&E1[t][w32 + g * 8 + hk4] = pk;
      }
    }
  }
  __syncthreads();

  // read-back: b128 LDS -> b128 coalesced global + post-bias column sums
  {
    const int colc = tid & 15, tgrp = tid >> 4;
    const int o8 = (colc & 7) * 8;
    half_t* __restrict__ base = (colc < 8) ? q : k;
    float sums[8];
    #pragma unroll
    for (int p = 0; p < 8; p++) sums[p] = 0.f;
    #pragma unroll
    for (int j = 0; j < 8; j++) {
      const int t = tgrp * 8 + j;
      const half8 v8 = *(const half8*)&E1[t][colc * 8];
      *(half8*)&base[w * 65536 + (t0 + t) * 64 + o8] = v8;
      #pragma unroll
      for (int p = 0; p < 8; p++) sums[p] += (float)v8[p];
    }
    float* sl = (colc < 8) ? qs_l : ks_l;
    #pragma unroll
    for (int p = 0; p < 8; p++) atomicAdd(&sl[o8 + p], sums[p]);
  }
  __syncthreads();
  if (tid < 64) {
    qp[(w * 8 + tx) * 64 + tid] = qs_l[tid];
    kp[(w * 8 + tx) * 64 + tid] = ks_l[tid];
  }
}

// ------------------------------------------------------------------ k_ar ----
// Reduce per-tile partials; arH[i][j] = (half)relu(qsum_i . ksum_j)/1024^2
__global__ __launch_bounds__(256) void k_ar(const float* __restrict__ qp,
                                            const float* __restrict__ kp,
                                            half_t* __restrict__ arH) {
  __shared__ float qs[64][65];
  __shared__ float ks[64][65];
  const int tid = threadIdx.x;
  for (int e = tid; e < 4096; e += 256) {
    const int i = e >> 6, c = e & 63;
    float sq = 0.f, sk = 0.f;
    #pragma unroll
    for (int t = 0; t < 8; t++) {
      sq += qp[i * 512 + t * 64 + c];
      sk += kp[i * 512 + t * 64 + c];
    }
    qs[i][c] = sq;
    ks[i][c] = sk;
  }
  __syncthreads();
  const float scale = 1.f / (1024.f * 1024.f);
  const int e = blockIdx.x * 256 + tid;  // grid 16 -> 4096 outputs
  const int i = e >> 6, j = e & 63;
  float s = 0.f;
  #pragma unroll
  for (int c = 0; c < 64; c++) s += qs[i][c] * ks[j][c];
  s *= scale;
  arH[e] = (half_t)(s > 0.f ? s : 0.f);
}

// ----------------------------------------------------------------- k_mix ----
// MFMA GEMM: D[i][pos] = sum_j arH[i][j] * src[j][pos].  M=64(i), K=64(j),
// N=65536(pos). A-frags = arH rows (b128, L1-hot). B-frags assembled from
// coalesced scalar u16 global loads (lane n=pos). C stored as coalesced u16.
// No LDS, no barriers. grid (256, 2): wave handles 2 pos-tiles of 32.
__global__ __launch_bounds__(256) void k_mix(const half_t* __restrict__ q,
                                             const half_t* __restrict__ k,
                                             const half_t* __restrict__ arH,
                                             half_t* __restrict__ qm,
                                             half_t* __restrict__ km) {
  const half_t* __restrict__ src = blockIdx.y ? k : q;
  half_t* __restrict__ dst = blockIdx.y ? km : qm;
  const int tid = threadIdx.x;
  const int wave = tid >> 6, lane = tid & 63;
  const int ln31 = lane & 31;
  const int hk8 = (lane >> 5) * 8;

  // A-frags: A[m=i][k=j], i = mt*32 + ln31, j = kk*16 + hk8 + jj
  half8 aA[2][4];
  #pragma unroll
  for (int mt = 0; mt < 2; mt++)
    #pragma unroll
    for (int kk = 0; kk < 4; kk++)
      aA[mt][kk] = *(const half8*)&arH[(mt * 32 + ln31) * 64 + kk * 16 + hk8];

  #pragma unroll
  for (int t32 = 0; t32 < 2; t32++) {
    const int pos = blockIdx.x * 256 + wave * 64 + t32 * 32 + ln31;
    // B-frags: B[k=j][n=pos]
    half8 bB[4];
    #pragma unroll
    for (int kk = 0; kk < 4; kk++)
      #pragma unroll
      for (int jj = 0; jj < 8; jj++)
        bB[kk][jj] = src[(kk * 16 + hk8 + jj) * 65536 + pos];

    floatx16 c0, c1;
    #pragma unroll
    for (int r = 0; r < 16; r++) { c0[r] = 0.f; c1[r] = 0.f; }
    #pragma unroll
    for (int kk = 0; kk < 4; kk++) {
      c0 = MFMA32(aA[0][kk], bB[kk], c0);
      c1 = MFMA32(aA[1][kk], bB[kk], c1);
    }
    // store: i = mt*32 + (r&3) + 4*(lane>>5) + 8*(r>>2), coalesced u16
    const int h4 = (lane >> 5) * 4;
    #pragma unroll
    for (int r = 0; r < 16; r++) {
      const int row = (r & 3) + h4 + 8 * (r >> 2);
      dst[row * 65536 + pos] = (half_t)c0[r];
      dst[(32 + row) * 65536 + pos] = (half_t)c1[r];
    }
  }
}

// ---------------------------------------------------------------- k_attn ----
// Per (t-tile of 128, window): O = relu(Qm Km^T) V over 8 s-chunks of 128.
// v4: only St lives in LDS (stride 136 -> 16B-aligned b64 writes / b128
// reads). K and Q frags direct from global; V A-frags direct from global
// (chunk is L1/L2-hot across the block's waves). O^T C-layout stores
// straight to out[c][h][w].
__global__ __launch_bounds__(256, 2) void k_attn(const half_t* __restrict__ qm,
                                                 const half_t* __restrict__ km,
                                                 const half_t* __restrict__ vT,
                                                 float* __restrict__ out) {
  __shared__ __align__(16) half_t St[128][136];  // [t][s], 34816 B
  const int w = blockIdx.y;
  const int t0 = blockIdx.x * 128;
  const int tid = threadIdx.x;
  const int wave = tid >> 6, lane = tid & 63;
  const int ln31 = lane & 31;
  const int hk8 = (lane >> 5) * 8, hk4 = (lane >> 5) * 4;
  const int w32 = wave * 32;
  const int wbase = w * 65536;

  // Q as B-fragments direct from global: B[n=t][k=c]
  half8 bQ[4][4];
  #pragma unroll
  for (int tt = 0; tt < 4; tt++)
    #pragma unroll
    for (int kk = 0; kk < 4; kk++)
      bQ[tt][kk] = *(const half8*)&qm[wbase + (t0 + tt * 32 + ln31) * 64 + kk * 16 + hk8];

  floatx16 oacc[2];
  #pragma unroll
  for (int ct = 0; ct < 2; ct++)
    #pragma unroll
    for (int r = 0; r < 16; r++) oacc[ct][r] = 0.f;

  for (int sc = 0; sc < 8; sc++) {
    const int s0 = sc * 128;
    // K A-frags direct from global (each s-row consumed by exactly one wave)
    half8 aK[4];
    #pragma unroll
    for (int kk = 0; kk < 4; kk++)
      aK[kk] = *(const half8*)&km[wbase + (s0 + w32 + ln31) * 64 + kk * 16 + hk8];

    // S^T[s][t] = sum_c K[s][c] Q[t][c]; wave owns s-rows [w32, w32+32)
    floatx16 sacc[4];
    #pragma unroll
    for (int tt = 0; tt < 4; tt++)
      #pragma unroll
      for (int r = 0; r < 16; r++) sacc[tt][r] = 0.f;
    #pragma unroll
    for (int kk = 0; kk < 4; kk++)
      #pragma unroll
      for (int tt = 0; tt < 4; tt++)
        sacc[tt] = MFMA32(aK[kk], bQ[tt][kk], sacc[tt]);

    __syncthreads();  // previous chunk's St reads done
    // relu -> packed half4 -> St[t][s]
    #pragma unroll
    for (int tt = 0; tt < 4; tt++) {
      const int t = tt * 32 + ln31;
      #pragma unroll
      for (int g = 0; g < 4; g++) {
        const int s = w32 + g * 8 + hk4;
        half4 pk;
        #pragma unroll
        for (int p = 0; p < 4; p++) {
          const float v = sacc[tt][g * 4 + p];
          pk[p] = (half_t)(v > 0.f ? v : 0.f);
        }
        *(half4*)&St[t][s] = pk;
      }
    }
    __syncthreads();  // St ready

    // O^T[c][t] += sum_s V^T[c][s] S[s][t]: A = vT rows direct from global,
    // B = St rows (n=t); wave owns t-cols [w32, w32+32)
    #pragma unroll
    for (int kk = 0; kk < 8; kk++) {
      const half8 bS = *(const half8*)&St[w32 + ln31][kk * 16 + hk8];
      #pragma unroll
      for (int ct = 0; ct < 2; ct++) {
        const half8 aV = *(const half8*)&vT[wbase + (ct * 32 + ln31) * 1024 + s0 + kk * 16 + hk8];
        oacc[ct] = MFMA32(aV, bS, oacc[ct]);
      }
    }
  }

  // Direct store: lane's col t = t0+w32+ln31 (fixed), rows c vary with reg.
  const int ih = w >> 3, iw = w & 7;
  const int obase = ih * 8192 + iw * 32;
  const int tb = ((t0 + w32) >> 5) * 256 + ln31;  // t0+w32 multiple of 32
  const int h4 = (lane >> 5) * 4;
  #pragma unroll
  for (int ct = 0; ct < 2; ct++) {
    #pragma unroll
    for (int r = 0; r < 16; r++) {
      const int c = ct * 32 + (r & 3) + h4 + 8 * (r >> 2);
      out[c * 65536 + obase + tb] = oacc[ct][r];
    }
  }
}

// ---------------------------------------------------------------- launch ----
extern "C" void kernel_launch(void* const* d_in, const int* in_sizes, int n_in,
                              void* d_out, int out_size, void* d_ws, size_t ws_size,
                              hipStream_t stream) {
  const float* x = (const float*)d_in[0];
  const float* W = (const float*)d_in[1];
  const float* bias = (const float*)d_in[2];
  float* out = (float*)d_out;

  half_t* q = (half_t*)d_ws;
  half_t* k = q + 4194304;
  half_t* vT = k + 4194304;
  half_t* qm = vT + 4194304;
  half_t* km = qm + 4194304;
  float* qp = (float*)(km + 4194304);  // 512*64
  float* kp = qp + 32768;
  half_t* arH = (half_t*)(kp + 32768); // 4096, 16B-aligned

  k_qkv<<<dim3(8, 64), 256, 0, stream>>>(x, W, bias, q, k, vT, qp, kp);
  k_ar<<<16, 256, 0, stream>>>(qp, kp, arH);
  k_mix<<<dim3(256, 2), 256, 0, stream>>>(q, k, arH, qm, km);
  k_attn<<<dim3(8, 64), 256, 0, stream>>>(qm, km, vT, out);
}

// Round 8
// 145.696 us; speedup vs baseline: 1.0633x; 1.0633x over previous
//
#include <hip/hip_runtime.h>

typedef _Float16 half_t;
typedef __attribute__((ext_vector_type(8))) _Float16 half8;
typedef __attribute__((ext_vector_type(4))) _Float16 half4;
typedef __attribute__((ext_vector_type(2))) __fp16 fp16x2;
typedef __attribute__((ext_vector_type(2))) float floatx2;
typedef __attribute__((ext_vector_type(4))) float floatx4;
typedef __attribute__((ext_vector_type(16))) float floatx16;

#define MFMA32(A, B, C) __builtin_amdgcn_mfma_f32_32x32x16_f16((A), (B), (C), 0, 0, 0)

union H2I { fp16x2 h; int i; };
union I4H8 { int i[4]; half8 h; };

static __device__ __forceinline__ int pack_relu(float a, float b) {
  H2I u;
  u.h = __builtin_amdgcn_cvt_pkrtz(a > 0.f ? a : 0.f, b > 0.f ? b : 0.f);
  return u.i;
}

// ----------------------------------------------------------------- k_qkv ----
// Per (t-tile tx, window w), 32x32x16 MFMA:
//   D1^T[o 0..127][t 0..127] = W[0:128] . Xw^T   (q,k — transposed form)
//   D2  [t 0..127][o 0..63]  = Xw . W[128:192]^T (v — natural form)
__global__ __launch_bounds__(256, 3) void k_qkv(
    const float* __restrict__ x, const float* __restrict__ W,
    const float* __restrict__ bias, half_t* __restrict__ q,
    half_t* __restrict__ k, half_t* __restrict__ vT,
    float* __restrict__ qp, float* __restrict__ kp) {
  __shared__ __align__(16) char smem[46080];  // Xs+Ws | E1 (overlaid)
  half_t (*Xs)[72] = (half_t (*)[72])smem;            // 18432 B [t][c]
  half_t (*Ws)[72] = (half_t (*)[72])(smem + 18432);  // 27648 B [o][c]
  half_t (*E1)[136] = (half_t (*)[136])smem;          // 34816 B [t][o], after barrier
  __shared__ float qs_l[64], ks_l[64];

  const int w = blockIdx.y, tx = blockIdx.x;
  const int t0 = tx * 128;
  const int ih = w >> 3, iw = w & 7;
  const int xbase = ih * 8192 + iw * 32;
  const int tid = threadIdx.x;

  if (tid < 64) { qs_l[tid] = 0.f; ks_l[tid] = 0.f; }

  {
    const int t = tid & 127, cg = tid >> 7;
    const int tg = t0 + t;
    const int xoff = xbase + (tg >> 5) * 256 + (tg & 31);
    half8 h8[4];
    #pragma unroll
    for (int m = 0; m < 32; m++)
      h8[m >> 3][m & 7] = (half_t)x[(cg * 32 + m) * 65536 + xoff];
    #pragma unroll
    for (int g = 0; g < 4; g++)
      *(half8*)&Xs[t][cg * 32 + g * 8] = h8[g];
  }
  for (int i = tid; i < 3072; i += 256) {
    const int o = i >> 4, c4 = (i & 15) * 4;
    const floatx4 v = *(const floatx4*)&W[o * 64 + c4];
    half4 hv;
    #pragma unroll
    for (int p = 0; p < 4; p++) hv[p] = (half_t)v[p];
    *(half4*)&Ws[o][c4] = hv;
  }
  __syncthreads();

  const int wave = tid >> 6, lane = tid & 63;
  const int ln31 = lane & 31;
  const int hk8 = (lane >> 5) * 8, hk4 = (lane >> 5) * 4;
  const int w32 = wave * 32;

  floatx16 d1[4], dv[2];
  #pragma unroll
  for (int tt = 0; tt < 4; tt++)
    #pragma unroll
    for (int r = 0; r < 16; r++) d1[tt][r] = 0.f;
  #pragma unroll
  for (int ot = 0; ot < 2; ot++)
    #pragma unroll
    for (int r = 0; r < 16; r++) dv[ot][r] = 0.f;

  #pragma unroll
  for (int kk = 0; kk < 4; kk++) {
    const int ko = kk * 16 + hk8;
    const half8 aW = *(const half8*)&Ws[w32 + ln31][ko];
    half8 bX[4];
    #pragma unroll
    for (int tt = 0; tt < 4; tt++)
      bX[tt] = *(const half8*)&Xs[tt * 32 + ln31][ko];
    const half8 bV0 = *(const half8*)&Ws[128 + ln31][ko];
    const half8 bV1 = *(const half8*)&Ws[160 + ln31][ko];
    #pragma unroll
    for (int tt = 0; tt < 4; tt++) d1[tt] = MFMA32(aW, bX[tt], d1[tt]);
    dv[0] = MFMA32(bX[wave], bV0, dv[0]);
    dv[1] = MFMA32(bX[wave], bV1, dv[1]);
  }

  {
    const int wbase = w * 65536;
    #pragma unroll
    for (int ot = 0; ot < 2; ot++) {
      const int o = ot * 32 + ln31;
      const float bv = bias[128 + o];
      #pragma unroll
      for (int g = 0; g < 4; g++) {
        const int tl = w32 + g * 8 + hk4;
        half4 pk;
        #pragma unroll
        for (int p = 0; p < 4; p++) pk[p] = (half_t)(dv[ot][g * 4 + p] + bv);
        *(half4*)&vT[wbase + o * 1024 + t0 + tl] = pk;
      }
    }
  }

  __syncthreads();

  {
    floatx4 b4[4];
    #pragma unroll
    for (int g = 0; g < 4; g++)
      b4[g] = *(const floatx4*)&bias[w32 + g * 8 + hk4];
    #pragma unroll
    for (int tt = 0; tt < 4; tt++) {
      const int t = tt * 32 + ln31;
      #pragma unroll
      for (int g = 0; g < 4; g++) {
        half4 pk;
        #pragma unroll
        for (int p = 0; p < 4; p++)
          pk[p] = (half_t)(d1[tt][g * 4 + p] + b4[g][p]);
        *(half4*)&E1[t][w32 + g * 8 + hk4] = pk;
      }
    }
  }
  __syncthreads();

  {
    const int colc = tid & 15, tgrp = tid >> 4;
    const int o8 = (colc & 7) * 8;
    half_t* __restrict__ base = (colc < 8) ? q : k;
    float sums[8];
    #pragma unroll
    for (int p = 0; p < 8; p++) sums[p] = 0.f;
    #pragma unroll
    for (int j = 0; j < 8; j++) {
      const int t = tgrp * 8 + j;
      const half8 v8 = *(const half8*)&E1[t][colc * 8];
      *(half8*)&base[w * 65536 + (t0 + t) * 64 + o8] = v8;
      #pragma unroll
      for (int p = 0; p < 8; p++) sums[p] += (float)v8[p];
    }
    float* sl = (colc < 8) ? qs_l : ks_l;
    #pragma unroll
    for (int p = 0; p < 8; p++) atomicAdd(&sl[o8 + p], sums[p]);
  }
  __syncthreads();
  if (tid < 64) {
    qp[(w * 8 + tx) * 64 + tid] = qs_l[tid];
    kp[(w * 8 + tx) * 64 + tid] = ks_l[tid];
  }
}

// ------------------------------------------------------------------ k_ar ----
__global__ __launch_bounds__(256) void k_ar(const float* __restrict__ qp,
                                            const float* __restrict__ kp,
                                            half_t* __restrict__ arH) {
  __shared__ float qs[64][65];
  __shared__ float ks[64][65];
  const int tid = threadIdx.x;
  for (int e = tid; e < 4096; e += 256) {
    const int i = e >> 6, c = e & 63;
    float sq = 0.f, sk = 0.f;
    #pragma unroll
    for (int t = 0; t < 8; t++) {
      sq += qp[i * 512 + t * 64 + c];
      sk += kp[i * 512 + t * 64 + c];
    }
    qs[i][c] = sq;
    ks[i][c] = sk;
  }
  __syncthreads();
  const float scale = 1.f / (1024.f * 1024.f);
  const int e = blockIdx.x * 256 + tid;
  const int i = e >> 6, j = e & 63;
  float s = 0.f;
  #pragma unroll
  for (int c = 0; c < 64; c++) s += qs[i][c] * ks[j][c];
  s *= scale;
  arH[e] = (half_t)(s > 0.f ? s : 0.f);
}

// ----------------------------------------------------------------- k_mix ----
__global__ __launch_bounds__(256) void k_mix(const half_t* __restrict__ q,
                                             const half_t* __restrict__ k,
                                             const half_t* __restrict__ arH,
                                             half_t* __restrict__ qm,
                                             half_t* __restrict__ km) {
  const half_t* __restrict__ src = blockIdx.y ? k : q;
  half_t* __restrict__ dst = blockIdx.y ? km : qm;
  const int tid = threadIdx.x;
  const int wave = tid >> 6, lane = tid & 63;
  const int ln31 = lane & 31;
  const int hk8 = (lane >> 5) * 8;

  half8 aA[2][4];
  #pragma unroll
  for (int mt = 0; mt < 2; mt++)
    #pragma unroll
    for (int kk = 0; kk < 4; kk++)
      aA[mt][kk] = *(const half8*)&arH[(mt * 32 + ln31) * 64 + kk * 16 + hk8];

  #pragma unroll
  for (int t32 = 0; t32 < 2; t32++) {
    const int pos = blockIdx.x * 256 + wave * 64 + t32 * 32 + ln31;
    half8 bB[4];
    #pragma unroll
    for (int kk = 0; kk < 4; kk++)
      #pragma unroll
      for (int jj = 0; jj < 8; jj++)
        bB[kk][jj] = src[(kk * 16 + hk8 + jj) * 65536 + pos];

    floatx16 c0, c1;
    #pragma unroll
    for (int r = 0; r < 16; r++) { c0[r] = 0.f; c1[r] = 0.f; }
    #pragma unroll
    for (int kk = 0; kk < 4; kk++) {
      c0 = MFMA32(aA[0][kk], bB[kk], c0);
      c1 = MFMA32(aA[1][kk], bB[kk], c1);
    }
    const int h4 = (lane >> 5) * 4;
    #pragma unroll
    for (int r = 0; r < 16; r++) {
      const int row = (r & 3) + h4 + 8 * (r >> 2);
      dst[row * 65536 + pos] = (half_t)c0[r];
      dst[(32 + row) * 65536 + pos] = (half_t)c1[r];
    }
  }
}

// ---------------------------------------------------------------- k_attn ----
// v5: barrier-free chunk loop. 4 waves = 2 s-halves x 2 t-halves; each wave
// computes S for its (s64 x t64) slice and consumes it in PV immediately.
// C-layout -> B-layout done in-register: half the fragment swapped with
// lane^32 via __shfl_xor (no LDS, no barriers). Partial O^T reduced across
// the s-half wave pairs once at the end via LDS. Grid swizzled so a
// window's 8 blocks share an XCD (km/vT re-reads hit L2).
__global__ __launch_bounds__(256, 2) void k_attn(const half_t* __restrict__ qm,
                                                 const half_t* __restrict__ km,
                                                 const half_t* __restrict__ vT,
                                                 float* __restrict__ out) {
  __shared__ float Lbuf[2][64][66];  // 33792 B: [t-half][lane][reg]
  const int L = blockIdx.x;
  const int w = (L & 7) | ((L >> 6) << 3);  // same-w blocks: same L%8 (XCD)
  const int t0 = ((L >> 3) & 7) * 128;
  const int tid = threadIdx.x;
  const int wave = tid >> 6, lane = tid & 63;
  const int ln31 = lane & 31;
  const int hq = lane >> 5;
  const int hk8 = hq * 8;
  const int th = wave & 1, sm2 = wave >> 1;
  const int tb = th * 64;   // wave's t-half within the 128-tile
  const int sb = sm2 * 64;  // wave's s-half within each 128-chunk
  const int wbase = w * 65536;

  // Q B-frags, resident: B[k=c][n=t], t = t0+tb+tt*32+ln31
  half8 bQ[2][4];
  #pragma unroll
  for (int tt = 0; tt < 2; tt++)
    #pragma unroll
    for (int kk = 0; kk < 4; kk++)
      bQ[tt][kk] = *(const half8*)&qm[wbase + (t0 + tb + tt * 32 + ln31) * 64 + kk * 16 + hk8];

  floatx16 oacc[2][2];  // [ct][tt] partial O^T over this wave's s-slices
  #pragma unroll
  for (int ct = 0; ct < 2; ct++)
    #pragma unroll
    for (int tt = 0; tt < 2; tt++)
      #pragma unroll
      for (int r = 0; r < 16; r++) oacc[ct][tt][r] = 0.f;

  for (int sc = 0; sc < 8; sc++) {
    const int s0 = sc * 128;
    // K A-frags: A[m=s][k=c], s = s0+sb+sm*32+ln31
    half8 aK[2][4];
    #pragma unroll
    for (int sm = 0; sm < 2; sm++)
      #pragma unroll
      for (int kk = 0; kk < 4; kk++)
        aK[sm][kk] = *(const half8*)&km[wbase + (s0 + sb + sm * 32 + ln31) * 64 + kk * 16 + hk8];
    // V A-frags: A[m=c][k=s], s = s0+sb+ko*16+hk8+j (independent -> early issue)
    half8 aV[2][4];
    #pragma unroll
    for (int ct = 0; ct < 2; ct++)
      #pragma unroll
      for (int ko = 0; ko < 4; ko++)
        aV[ct][ko] = *(const half8*)&vT[wbase + (ct * 32 + ln31) * 1024 + s0 + sb + ko * 16 + hk8];

    // S^T slice: rows s (m), cols t (n)
    floatx16 sacc[2][2];
    #pragma unroll
    for (int sm = 0; sm < 2; sm++)
      #pragma unroll
      for (int tt = 0; tt < 2; tt++)
        #pragma unroll
        for (int r = 0; r < 16; r++) sacc[sm][tt][r] = 0.f;
    #pragma unroll
    for (int kk = 0; kk < 4; kk++)
      #pragma unroll
      for (int sm = 0; sm < 2; sm++)
        #pragma unroll
        for (int tt = 0; tt < 2; tt++)
          sacc[sm][tt] = MFMA32(aK[sm][kk], bQ[tt][kk], sacc[sm][tt]);

    // relu -> half2 pack -> build B-frags bS[tt][ko] (k = wave's s-slice).
    // Lane has s32 = 8m+4hq+(r&3); the 4(1-hq) half comes from lane^32.
    half8 bS[2][4];
    #pragma unroll
    for (int sm = 0; sm < 2; sm++)
      #pragma unroll
      for (int tt = 0; tt < 2; tt++) {
        int p[8];
        #pragma unroll
        for (int i = 0; i < 8; i++)
          p[i] = pack_relu(sacc[sm][tt][2 * i], sacc[sm][tt][2 * i + 1]);
        // send groups partner needs: m' = {1-hq, 3-hq}
        const int pl0 = hq ? p[0] : p[2];
        const int pl1 = hq ? p[1] : p[3];
        const int pl2 = hq ? p[4] : p[6];
        const int pl3 = hq ? p[5] : p[7];
        const int rv0 = __shfl_xor(pl0, 32, 64);
        const int rv1 = __shfl_xor(pl1, 32, 64);
        const int rv2 = __shfl_xor(pl2, 32, 64);
        const int rv3 = __shfl_xor(pl3, 32, 64);
        #pragma unroll
        for (int kb = 0; kb < 2; kb++) {
          const int o0 = p[4 * kb + 2 * hq], o1 = p[4 * kb + 2 * hq + 1];
          const int r0 = kb ? rv2 : rv0, r1 = kb ? rv3 : rv1;
          I4H8 u;
          u.i[0] = hq ? r0 : o0;  // j0,j1 from hq=0 holder
          u.i[1] = hq ? r1 : o1;
          u.i[2] = hq ? o0 : r0;  // j4,j5 from hq=1 holder
          u.i[3] = hq ? o1 : r1;
          bS[tt][sm * 2 + kb] = u.h;
        }
      }

    // O^T[c][t] += V^T . S over this wave's 64-long s-slice
    #pragma unroll
    for (int ko = 0; ko < 4; ko++)
      #pragma unroll
      for (int ct = 0; ct < 2; ct++)
        #pragma unroll
        for (int tt = 0; tt < 2; tt++)
          oacc[ct][tt] = MFMA32(aV[ct][ko], bS[tt][ko], oacc[ct][tt]);
  }

  // cross-wave reduce: sm2=1 waves dump, sm2=0 waves add + store
  if (sm2 == 1) {
    #pragma unroll
    for (int ct = 0; ct < 2; ct++)
      #pragma unroll
      for (int tt = 0; tt < 2; tt++)
        #pragma unroll
        for (int r = 0; r < 16; r += 2) {
          floatx2 v2 = {oacc[ct][tt][r], oacc[ct][tt][r + 1]};
          *(floatx2*)&Lbuf[th][lane][(ct * 2 + tt) * 16 + r] = v2;
        }
  }
  __syncthreads();
  if (sm2 == 0) {
    const int ih = w >> 3, iw = w & 7;
    const int obase = ih * 8192 + iw * 32;
    #pragma unroll
    for (int tt = 0; tt < 2; tt++) {
      const int tcol = ((t0 + tb + tt * 32) >> 5) * 256 + ln31;
      #pragma unroll
      for (int ct = 0; ct < 2; ct++) {
        #pragma unroll
        for (int r = 0; r < 16; r++) {
          const float v = oacc[ct][tt][r] + Lbuf[th][lane][(ct * 2 + tt) * 16 + r];
          const int c = ct * 32 + (r & 3) + 4 * hq + 8 * (r >> 2);
          out[c * 65536 + obase + tcol] = v;
        }
      }
    }
  }
}

// ---------------------------------------------------------------- launch ----
extern "C" void kernel_launch(void* const* d_in, const int* in_sizes, int n_in,
                              void* d_out, int out_size, void* d_ws, size_t ws_size,
                              hipStream_t stream) {
  const float* x = (const float*)d_in[0];
  const float* W = (const float*)d_in[1];
  const float* bias = (const float*)d_in[2];
  float* out = (float*)d_out;

  half_t* q = (half_t*)d_ws;
  half_t* k = q + 4194304;
  half_t* vT = k + 4194304;
  half_t* qm = vT + 4194304;
  half_t* km = qm + 4194304;
  float* qp = (float*)(km + 4194304);  // 512*64
  float* kp = qp + 32768;
  half_t* arH = (half_t*)(kp + 32768); // 4096, 16B-aligned

  k_qkv<<<dim3(8, 64), 256, 0, stream>>>(x, W, bias, q, k, vT, qp, kp);
  k_ar<<<16, 256, 0, stream>>>(qp, kp, arH);
  k_mix<<<dim3(256, 2), 256, 0, stream>>>(q, k, arH, qm, km);
  k_attn<<<512, 256, 0, stream>>>(qm, km, vT, out);
}

// Round 9
// 141.572 us; speedup vs baseline: 1.0943x; 1.0291x over previous
//
#include <hip/hip_runtime.h>

typedef _Float16 half_t;
typedef __attribute__((ext_vector_type(8))) _Float16 half8;
typedef __attribute__((ext_vector_type(4))) _Float16 half4;
typedef __attribute__((ext_vector_type(4))) float floatx4;
typedef __attribute__((ext_vector_type(16))) float floatx16;

#define MFMA32(A, B, C) __builtin_amdgcn_mfma_f32_32x32x16_f16((A), (B), (C), 0, 0, 0)

// ----------------------------------------------------------------- k_qkv ----
// Per (t-tile tx, window w), 32x32x16 MFMA:
//   D1^T[o 0..127][t 0..127] = W[0:128] . Xw^T   (q,k — transposed form)
//   D2  [t 0..127][o 0..63]  = Xw . W[128:192]^T (v — natural form)
__global__ __launch_bounds__(256, 3) void k_qkv(
    const float* __restrict__ x, const float* __restrict__ W,
    const float* __restrict__ bias, half_t* __restrict__ q,
    half_t* __restrict__ k, half_t* __restrict__ vT,
    float* __restrict__ qp, float* __restrict__ kp) {
  __shared__ __align__(16) char smem[46080];  // Xs+Ws | E1 (overlaid)
  half_t (*Xs)[72] = (half_t (*)[72])smem;            // 18432 B [t][c]
  half_t (*Ws)[72] = (half_t (*)[72])(smem + 18432);  // 27648 B [o][c]
  half_t (*E1)[136] = (half_t (*)[136])smem;          // 34816 B [t][o], after barrier
  __shared__ float qs_l[64], ks_l[64];

  const int w = blockIdx.y, tx = blockIdx.x;
  const int t0 = tx * 128;
  const int ih = w >> 3, iw = w & 7;
  const int xbase = ih * 8192 + iw * 32;
  const int tid = threadIdx.x;

  if (tid < 64) { qs_l[tid] = 0.f; ks_l[tid] = 0.f; }

  {
    const int t = tid & 127, cg = tid >> 7;
    const int tg = t0 + t;
    const int xoff = xbase + (tg >> 5) * 256 + (tg & 31);
    half8 h8[4];
    #pragma unroll
    for (int m = 0; m < 32; m++)
      h8[m >> 3][m & 7] = (half_t)x[(cg * 32 + m) * 65536 + xoff];
    #pragma unroll
    for (int g = 0; g < 4; g++)
      *(half8*)&Xs[t][cg * 32 + g * 8] = h8[g];
  }
  for (int i = tid; i < 3072; i += 256) {
    const int o = i >> 4, c4 = (i & 15) * 4;
    const floatx4 v = *(const floatx4*)&W[o * 64 + c4];
    half4 hv;
    #pragma unroll
    for (int p = 0; p < 4; p++) hv[p] = (half_t)v[p];
    *(half4*)&Ws[o][c4] = hv;
  }
  __syncthreads();

  const int wave = tid >> 6, lane = tid & 63;
  const int ln31 = lane & 31;
  const int hk8 = (lane >> 5) * 8, hk4 = (lane >> 5) * 4;
  const int w32 = wave * 32;

  floatx16 d1[4], dv[2];
  #pragma unroll
  for (int tt = 0; tt < 4; tt++)
    #pragma unroll
    for (int r = 0; r < 16; r++) d1[tt][r] = 0.f;
  #pragma unroll
  for (int ot = 0; ot < 2; ot++)
    #pragma unroll
    for (int r = 0; r < 16; r++) dv[ot][r] = 0.f;

  #pragma unroll
  for (int kk = 0; kk < 4; kk++) {
    const int ko = kk * 16 + hk8;
    const half8 aW = *(const half8*)&Ws[w32 + ln31][ko];
    half8 bX[4];
    #pragma unroll
    for (int tt = 0; tt < 4; tt++)
      bX[tt] = *(const half8*)&Xs[tt * 32 + ln31][ko];
    const half8 bV0 = *(const half8*)&Ws[128 + ln31][ko];
    const half8 bV1 = *(const half8*)&Ws[160 + ln31][ko];
    #pragma unroll
    for (int tt = 0; tt < 4; tt++) d1[tt] = MFMA32(aW, bX[tt], d1[tt]);
    dv[0] = MFMA32(bX[wave], bV0, dv[0]);
    dv[1] = MFMA32(bX[wave], bV1, dv[1]);
  }

  {
    const int wbase = w * 65536;
    #pragma unroll
    for (int ot = 0; ot < 2; ot++) {
      const int o = ot * 32 + ln31;
      const float bv = bias[128 + o];
      #pragma unroll
      for (int g = 0; g < 4; g++) {
        const int tl = w32 + g * 8 + hk4;
        half4 pk;
        #pragma unroll
        for (int p = 0; p < 4; p++) pk[p] = (half_t)(dv[ot][g * 4 + p] + bv);
        *(half4*)&vT[wbase + o * 1024 + t0 + tl] = pk;
      }
    }
  }

  __syncthreads();

  {
    floatx4 b4[4];
    #pragma unroll
    for (int g = 0; g < 4; g++)
      b4[g] = *(const floatx4*)&bias[w32 + g * 8 + hk4];
    #pragma unroll
    for (int tt = 0; tt < 4; tt++) {
      const int t = tt * 32 + ln31;
      #pragma unroll
      for (int g = 0; g < 4; g++) {
        half4 pk;
        #pragma unroll
        for (int p = 0; p < 4; p++)
          pk[p] = (half_t)(d1[tt][g * 4 + p] + b4[g][p]);
        *(half4*)&E1[t][w32 + g * 8 + hk4] = pk;
      }
    }
  }
  __syncthreads();

  {
    const int colc = tid & 15, tgrp = tid >> 4;
    const int o8 = (colc & 7) * 8;
    half_t* __restrict__ base = (colc < 8) ? q : k;
    float sums[8];
    #pragma unroll
    for (int p = 0; p < 8; p++) sums[p] = 0.f;
    #pragma unroll
    for (int j = 0; j < 8; j++) {
      const int t = tgrp * 8 + j;
      const half8 v8 = *(const half8*)&E1[t][colc * 8];
      *(half8*)&base[w * 65536 + (t0 + t) * 64 + o8] = v8;
      #pragma unroll
      for (int p = 0; p < 8; p++) sums[p] += (float)v8[p];
    }
    float* sl = (colc < 8) ? qs_l : ks_l;
    #pragma unroll
    for (int p = 0; p < 8; p++) atomicAdd(&sl[o8 + p], sums[p]);
  }
  __syncthreads();
  if (tid < 64) {
    qp[(w * 8 + tx) * 64 + tid] = qs_l[tid];
    kp[(w * 8 + tx) * 64 + tid] = ks_l[tid];
  }
}

// ------------------------------------------------------------------ k_ar ----
__global__ __launch_bounds__(256) void k_ar(const float* __restrict__ qp,
                                            const float* __restrict__ kp,
                                            half_t* __restrict__ arH) {
  __shared__ float qs[64][65];
  __shared__ float ks[64][65];
  const int tid = threadIdx.x;
  for (int e = tid; e < 4096; e += 256) {
    const int i = e >> 6, c = e & 63;
    float sq = 0.f, sk = 0.f;
    #pragma unroll
    for (int t = 0; t < 8; t++) {
      sq += qp[i * 512 + t * 64 + c];
      sk += kp[i * 512 + t * 64 + c];
    }
    qs[i][c] = sq;
    ks[i][c] = sk;
  }
  __syncthreads();
  const float scale = 1.f / (1024.f * 1024.f);
  const int e = blockIdx.x * 256 + tid;
  const int i = e >> 6, j = e & 63;
  float s = 0.f;
  #pragma unroll
  for (int c = 0; c < 64; c++) s += qs[i][c] * ks[j][c];
  s *= scale;
  arH[e] = (half_t)(s > 0.f ? s : 0.f);
}

// ----------------------------------------------------------------- k_mix ----
__global__ __launch_bounds__(256) void k_mix(const half_t* __restrict__ q,
                                             const half_t* __restrict__ k,
                                             const half_t* __restrict__ arH,
                                             half_t* __restrict__ qm,
                                             half_t* __restrict__ km) {
  const half_t* __restrict__ src = blockIdx.y ? k : q;
  half_t* __restrict__ dst = blockIdx.y ? km : qm;
  const int tid = threadIdx.x;
  const int wave = tid >> 6, lane = tid & 63;
  const int ln31 = lane & 31;
  const int hk8 = (lane >> 5) * 8;

  half8 aA[2][4];
  #pragma unroll
  for (int mt = 0; mt < 2; mt++)
    #pragma unroll
    for (int kk = 0; kk < 4; kk++)
      aA[mt][kk] = *(const half8*)&arH[(mt * 32 + ln31) * 64 + kk * 16 + hk8];

  #pragma unroll
  for (int t32 = 0; t32 < 2; t32++) {
    const int pos = blockIdx.x * 256 + wave * 64 + t32 * 32 + ln31;
    half8 bB[4];
    #pragma unroll
    for (int kk = 0; kk < 4; kk++)
      #pragma unroll
      for (int jj = 0; jj < 8; jj++)
        bB[kk][jj] = src[(kk * 16 + hk8 + jj) * 65536 + pos];

    floatx16 c0, c1;
    #pragma unroll
    for (int r = 0; r < 16; r++) { c0[r] = 0.f; c1[r] = 0.f; }
    #pragma unroll
    for (int kk = 0; kk < 4; kk++) {
      c0 = MFMA32(aA[0][kk], bB[kk], c0);
      c1 = MFMA32(aA[1][kk], bB[kk], c1);
    }
    const int h4 = (lane >> 5) * 4;
    #pragma unroll
    for (int r = 0; r < 16; r++) {
      const int row = (r & 3) + h4 + 8 * (r >> 2);
      dst[row * 65536 + pos] = (half_t)c0[r];
      dst[(32 + row) * 65536 + pos] = (half_t)c1[r];
    }
  }
}

// ---------------------------------------------------------------- k_attn ----
// v6 = v3 structure (best measured: ~25 us) + XCD swizzle + aligned St.
// Per (t-tile of 128, window): O = relu(Qm Km^T) V over 8 s-chunks of 128.
// Vs staged via coalesced half8 (scatter-free); K/Q frags direct global
// (few loads, L2-hot after swizzle); St stride 136 (272 B rows, 16B-aligned
// -> true b64 writes / b128 reads). O^T C-layout stores straight to out.
__global__ __launch_bounds__(256, 2) void k_attn(const half_t* __restrict__ qm,
                                                 const half_t* __restrict__ km,
                                                 const half_t* __restrict__ vT,
                                                 float* __restrict__ out) {
  __shared__ __align__(16) half_t Vs[64][136];   // [c][s-chunk] 17408 B
  __shared__ __align__(16) half_t St[128][136];  // [t][s]       34816 B
  const int L = blockIdx.x;
  const int w = (L & 7) | ((L >> 6) << 3);  // window's 8 blocks share L%8 (XCD)
  const int t0 = ((L >> 3) & 7) * 128;
  const int tid = threadIdx.x;
  const int wave = tid >> 6, lane = tid & 63;
  const int ln31 = lane & 31;
  const int hk8 = (lane >> 5) * 8, hk4 = (lane >> 5) * 4;
  const int w32 = wave * 32;
  const int wbase = w * 65536;

  // Q as B-fragments direct from global: B[n=t][k=c]
  half8 bQ[4][4];
  #pragma unroll
  for (int tt = 0; tt < 4; tt++)
    #pragma unroll
    for (int kk = 0; kk < 4; kk++)
      bQ[tt][kk] = *(const half8*)&qm[wbase + (t0 + tt * 32 + ln31) * 64 + kk * 16 + hk8];

  floatx16 oacc[2];
  #pragma unroll
  for (int ct = 0; ct < 2; ct++)
    #pragma unroll
    for (int r = 0; r < 16; r++) oacc[ct][r] = 0.f;

  for (int sc = 0; sc < 8; sc++) {
    const int s0 = sc * 128;
    __syncthreads();  // previous chunk's Vs/St reads done
    for (int idx = tid; idx < 1024; idx += 256) {
      const int c = idx >> 4, so = (idx & 15) * 8;
      *(half8*)&Vs[c][so] = *(const half8*)&vT[wbase + c * 1024 + s0 + so];
    }
    // K A-frags direct from global (each s-row consumed by exactly one wave)
    half8 aK[4];
    #pragma unroll
    for (int kk = 0; kk < 4; kk++)
      aK[kk] = *(const half8*)&km[wbase + (s0 + w32 + ln31) * 64 + kk * 16 + hk8];
    __syncthreads();  // Vs ready

    // S^T[s][t] = sum_c K[s][c] Q[t][c]; wave owns s-rows [w32, w32+32)
    floatx16 sacc[4];
    #pragma unroll
    for (int tt = 0; tt < 4; tt++)
      #pragma unroll
      for (int r = 0; r < 16; r++) sacc[tt][r] = 0.f;
    #pragma unroll
    for (int kk = 0; kk < 4; kk++)
      #pragma unroll
      for (int tt = 0; tt < 4; tt++)
        sacc[tt] = MFMA32(aK[kk], bQ[tt][kk], sacc[tt]);

    // relu -> packed half4 -> St[t][s] (row = 272 B, 16B-aligned)
    #pragma unroll
    for (int tt = 0; tt < 4; tt++) {
      const int t = tt * 32 + ln31;
      #pragma unroll
      for (int g = 0; g < 4; g++) {
        const int s = w32 + g * 8 + hk4;
        half4 pk;
        #pragma unroll
        for (int p = 0; p < 4; p++) {
          const float v = sacc[tt][g * 4 + p];
          pk[p] = (half_t)(v > 0.f ? v : 0.f);
        }
        *(half4*)&St[t][s] = pk;
      }
    }
    __syncthreads();  // St ready

    // O^T[c][t] += sum_s V^T[c][s] S[s][t]: A=Vs rows (m=c), B=St rows (n=t)
    #pragma unroll
    for (int kk = 0; kk < 8; kk++) {
      const half8 bS = *(const half8*)&St[w32 + ln31][kk * 16 + hk8];
      #pragma unroll
      for (int ct = 0; ct < 2; ct++) {
        const half8 aV = *(const half8*)&Vs[ct * 32 + ln31][kk * 16 + hk8];
        oacc[ct] = MFMA32(aV, bS, oacc[ct]);
      }
    }
  }

  // Direct store: lane's col t = t0+w32+ln31 (fixed), rows c vary with reg.
  const int ih = w >> 3, iw = w & 7;
  const int obase = ih * 8192 + iw * 32;
  const int tb = ((t0 + w32) >> 5) * 256 + ln31;  // t0+w32 multiple of 32
  const int h4 = (lane >> 5) * 4;
  #pragma unroll
  for (int ct = 0; ct < 2; ct++) {
    #pragma unroll
    for (int r = 0; r < 16; r++) {
      const int c = ct * 32 + (r & 3) + h4 + 8 * (r >> 2);
      out[c * 65536 + obase + tb] = oacc[ct][r];
    }
  }
}

// ---------------------------------------------------------------- launch ----
extern "C" void kernel_launch(void* const* d_in, const int* in_sizes, int n_in,
                              void* d_out, int out_size, void* d_ws, size_t ws_size,
                              hipStream_t stream) {
  const float* x = (const float*)d_in[0];
  const float* W = (const float*)d_in[1];
  const float* bias = (const float*)d_in[2];
  float* out = (float*)d_out;

  half_t* q = (half_t*)d_ws;
  half_t* k = q + 4194304;
  half_t* vT = k + 4194304;
  half_t* qm = vT + 4194304;
  half_t* km = qm + 4194304;
  float* qp = (float*)(km + 4194304);  // 512*64
  float* kp = qp + 32768;
  half_t* arH = (half_t*)(kp + 32768); // 4096, 16B-aligned

  k_qkv<<<dim3(8, 64), 256, 0, stream>>>(x, W, bias, q, k, vT, qp, kp);
  k_ar<<<16, 256, 0, stream>>>(qp, kp, arH);
  k_mix<<<dim3(256, 2), 256, 0, stream>>>(q, k, arH, qm, km);
  k_attn<<<512, 256, 0, stream>>>(qm, km, vT, out);
}